// Round 1
// baseline (180.080 us; speedup 1.0000x reference)
//
#include <hip/hip_runtime.h>

// EMA along contiguous T axis.
// Shapes: mag_spec [NSEQ=4112, T=6000] f32, initial_state [NSEQ] f32, weights [1] f32.
// out [NSEQ, T] f32.
//
// Strategy: one block per sequence. Stage sequence in LDS (coalesced float4),
// per-thread serial scan over K=25 elements as an affine map (A,B),
// shfl-based exclusive scan of affine maps across threads, then re-run the
// K-element loop with the correct incoming state and store coalesced.

constexpr int T_LEN = 6000;
constexpr int K_PER_THREAD = 25;                 // stride 25 is coprime with 32 banks -> 2-way max (free)
constexpr int N_ACTIVE = T_LEN / K_PER_THREAD;   // 240
constexpr int BLOCK = 256;

__global__ __launch_bounds__(BLOCK) void ema_kernel(
    const float* __restrict__ x,      // [NSEQ, T]
    const float* __restrict__ init,   // [NSEQ]
    const float* __restrict__ wptr,   // [1]
    float* __restrict__ out)          // [NSEQ, T]
{
    __shared__ float tile[T_LEN];
    __shared__ float waveA[4];
    __shared__ float waveB[4];

    const int seq = blockIdx.x;
    const int tid = threadIdx.x;
    const int lane = tid & 63;
    const int wid = tid >> 6;

    const float w = fminf(fmaxf(wptr[0], 0.0f), 1.0f);
    const float d = 1.0f - w;

    const float* xs = x + (size_t)seq * T_LEN;
    float* os = out + (size_t)seq * T_LEN;

    // ---- 1. coalesced float4 load into LDS (6000/4 = 1500 float4) ----
    {
        const float4* xs4 = (const float4*)xs;
        float4* tile4 = (float4*)tile;
        #pragma unroll
        for (int i = 0; i < (T_LEN / 4 + BLOCK - 1) / BLOCK; ++i) {
            int idx = tid + i * BLOCK;
            if (idx < T_LEN / 4) tile4[idx] = xs4[idx];
        }
    }
    __syncthreads();

    // ---- 2. per-thread affine map over its K elements: s_out = A*s_in + B ----
    float A = 1.0f, B = 0.0f;
    if (tid < N_ACTIVE) {
        const int base = tid * K_PER_THREAD;
        #pragma unroll
        for (int j = 0; j < K_PER_THREAD; ++j) {
            float xv = tile[base + j];
            B = fmaf(w, xv, d * B);
            A *= d;
        }
    }

    // ---- 3. inclusive shfl scan of affine maps within wave (width 64) ----
    float a = A, b = B;
    #pragma unroll
    for (int off = 1; off < 64; off <<= 1) {
        float pa = __shfl_up(a, off, 64);
        float pb = __shfl_up(b, off, 64);
        if (lane >= off) {
            // combine earlier (pa,pb) then current (a,b): s -> a*(pa*s+pb)+b
            b = fmaf(a, pb, b);
            a = a * pa;
        }
    }
    // wave aggregates
    if (lane == 63) { waveA[wid] = a; waveB[wid] = b; }
    __syncthreads();

    // exclusive prefix over earlier waves (serial over <=3 entries, all threads)
    float pA = 1.0f, pB = 0.0f;
    for (int i = 0; i < wid; ++i) {
        // apply wave i aggregate after current prefix
        pB = fmaf(waveA[i], pB, waveB[i]);
        pA = waveA[i] * pA;
    }

    // lane-exclusive within wave (shift inclusive scan by 1)
    float ea = __shfl_up(a, 1, 64);
    float eb = __shfl_up(b, 1, 64);
    if (lane == 0) { ea = 1.0f; eb = 0.0f; }

    // total exclusive prefix for this thread: s -> ea*(pA*s+pB)+eb
    const float Aex = ea * pA;
    const float Bex = fmaf(ea, pB, eb);

    // ---- 4. re-run chunk with correct incoming state, write in place ----
    if (tid < N_ACTIVE) {
        const float s0 = init[seq];
        float acc = fmaf(Aex, s0, Bex);
        const int base = tid * K_PER_THREAD;
        #pragma unroll
        for (int j = 0; j < K_PER_THREAD; ++j) {
            acc = fmaf(w, tile[base + j], d * acc);
            tile[base + j] = acc;
        }
    }
    __syncthreads();

    // ---- 5. coalesced float4 store ----
    {
        float4* os4 = (float4*)os;
        const float4* tile4 = (const float4*)tile;
        #pragma unroll
        for (int i = 0; i < (T_LEN / 4 + BLOCK - 1) / BLOCK; ++i) {
            int idx = tid + i * BLOCK;
            if (idx < T_LEN / 4) os4[idx] = tile4[idx];
        }
    }
}

extern "C" void kernel_launch(void* const* d_in, const int* in_sizes, int n_in,
                              void* d_out, int out_size, void* d_ws, size_t ws_size,
                              hipStream_t stream) {
    const float* mag_spec = (const float*)d_in[0];
    const float* initial_state = (const float*)d_in[1];
    const float* weights = (const float*)d_in[2];
    float* out = (float*)d_out;

    const int nseq = in_sizes[1];  // 8*2*257 = 4112 (initial_state has one elem per seq)

    ema_kernel<<<nseq, BLOCK, 0, stream>>>(mag_spec, initial_state, weights, out);
}